// Round 3
// baseline (222.504 us; speedup 1.0000x reference)
//
#include <hip/hip_runtime.h>
#include <hip/hip_bf16.h>

// Problem: lstm_20169166422798
// x:(64,512,513) W_ih:(200,513) W_hh:(200,50) b_ih:(200) b_hh:(200)
// W_out:(513,50) b_out:(513)  -> out:(64,512,513) fp32

#define B_SZ 64
#define T_SZ 512
#define F_SZ 513
#define H_SZ 50
#define G_SZ 200            // 4*H
#define M_SZ (B_SZ * T_SZ)  // 32768

typedef __attribute__((ext_vector_type(8))) short short8;   // bf16x8 MFMA frag
typedef __attribute__((ext_vector_type(4))) float f32x4;    // MFMA acc
typedef __attribute__((ext_vector_type(4), aligned(4))) float f32x4u;  // 4B-aligned vec load
typedef __attribute__((ext_vector_type(2))) float f32x2;    // packed-FMA pair

__device__ __forceinline__ float bf2f(unsigned short u) {
  unsigned int v = ((unsigned int)u) << 16;
  return __builtin_bit_cast(float, v);
}
__device__ __forceinline__ unsigned short f2bf(float f) {
  unsigned int b = __builtin_bit_cast(unsigned int, f);
  unsigned int r = b + 0x7FFFu + ((b >> 16) & 1u);
  return (unsigned short)(r >> 16);
}

// --------------- K0w: W_ih and W_out -> bf16 MFMA fragments (consumption order)
// Wf_ih[((t*13+nt)*64+lane)] : n=nt*16+(lane&15), k=t*32+(lane>>4)*8+j, t=0..16
// Wf_out[((t*33+nt)*64+lane)]: n=nt*16+(lane&15), k=t*32+(lane>>4)*8+j, t=0..1
#define NF_IH (17 * 13 * 64)
#define NF_OUT (2 * 33 * 64)
__global__ __launch_bounds__(256) void conv_weights(
    const float* __restrict__ Wih, const float* __restrict__ Wout,
    unsigned short* __restrict__ Wf_ih, unsigned short* __restrict__ Wf_out) {
  int idx = blockIdx.x * 256 + threadIdx.x;
  if (idx < NF_IH) {
    int lane = idx & 63;
    int nt = (idx >> 6) % 13;
    int t = idx / (13 * 64);
    int n = nt * 16 + (lane & 15);
    int k0 = t * 32 + (lane >> 4) * 8;
    short8 v;
#pragma unroll
    for (int j = 0; j < 8; j++) {
      int k = k0 + j;
      v[j] = (n < G_SZ && k < F_SZ) ? (short)f2bf(Wih[(size_t)n * F_SZ + k])
                                    : (short)0;
    }
    *(short8*)(Wf_ih + (size_t)idx * 8) = v;
  } else if (idx < NF_IH + NF_OUT) {
    int id2 = idx - NF_IH;
    int lane = id2 & 63;
    int nt = (id2 >> 6) % 33;
    int t = id2 / (33 * 64);
    int n = nt * 16 + (lane & 15);
    int k0 = t * 32 + (lane >> 4) * 8;
    short8 v;
#pragma unroll
    for (int j = 0; j < 8; j++) {
      int k = k0 + j;
      v[j] = (n < F_SZ && k < H_SZ) ? (short)f2bf(Wout[(size_t)n * H_SZ + k])
                                    : (short)0;
    }
    *(short8*)(Wf_out + (size_t)id2 * 8) = v;
  }
}

// ---------------------------------------------------------------- K1: xg GEMM
// xg(32768 x 200, bf16) = x(32768 x 513, fp32, converted in-register) @ W_ih^T
// + b_ih.  Latency fix: depth-4 named-register ping-pong prefetch of the x
// slabs (static indexing only) + __launch_bounds__(256,2) so the register
// allocator can hold ~4 slabs + hoisted Wf loads in flight (r1: VGPR=76 capped
// in-flight bytes -> all counters <16%).  Full unroll over the 16 slabs.
// Bounds: xr = row + kg*8 (kg*8 <= 24); max load idx 480+24+7 = 511 < 513.
__global__ __launch_bounds__(256, 2) void gemm_xg_mfma(
    const float* __restrict__ x, const unsigned short* __restrict__ Wf,
    const float* __restrict__ bih, unsigned short* __restrict__ xg) {
  int wave = threadIdx.x >> 6;
  int lane = threadIdx.x & 63;
  int m0 = blockIdx.x * 64 + wave * 16;
  int arow = lane & 15;  // m within tile
  int kg = lane >> 4;

  f32x4 acc[13];
#pragma unroll
  for (int nt = 0; nt < 13; nt++) acc[nt] = (f32x4){0.f, 0.f, 0.f, 0.f};

  const float* xr = x + (size_t)(m0 + arow) * F_SZ + kg * 8;  // lane's k-origin
  const short8* Bf = (const short8*)Wf;

  auto cvt8 = [](f32x4u lo, f32x4u hi) {
    short8 af;
#pragma unroll
    for (int jj = 0; jj < 4; jj++) af[jj] = (short)f2bf(lo[jj]);
#pragma unroll
    for (int jj = 0; jj < 4; jj++) af[4 + jj] = (short)f2bf(hi[jj]);
    return af;
  };
  auto mfma13 = [&](int t, short8 af) {
#pragma unroll
    for (int nt = 0; nt < 13; nt++) {
      short8 bf = Bf[(t * 13 + nt) * 64 + lane];
      acc[nt] = __builtin_amdgcn_mfma_f32_16x16x32_bf16(bf, af, acc[nt], 0, 0, 0);
    }
  };

  // depth-4 slab pipeline: named regs (no runtime indexing -> no scratch)
  f32x4u pa0 = *(const f32x4u*)(xr + 0 * 32), pa1 = *(const f32x4u*)(xr + 0 * 32 + 4);
  f32x4u pb0 = *(const f32x4u*)(xr + 1 * 32), pb1 = *(const f32x4u*)(xr + 1 * 32 + 4);
  f32x4u pc0 = *(const f32x4u*)(xr + 2 * 32), pc1 = *(const f32x4u*)(xr + 2 * 32 + 4);
  f32x4u pd0 = *(const f32x4u*)(xr + 3 * 32), pd1 = *(const f32x4u*)(xr + 3 * 32 + 4);

#pragma unroll
  for (int t = 0; t < 16; t += 4) {
    short8 af = cvt8(pa0, pa1);
    if (t + 4 < 16) { pa0 = *(const f32x4u*)(xr + (t + 4) * 32); pa1 = *(const f32x4u*)(xr + (t + 4) * 32 + 4); }
    mfma13(t, af);

    af = cvt8(pb0, pb1);
    if (t + 5 < 16) { pb0 = *(const f32x4u*)(xr + (t + 5) * 32); pb1 = *(const f32x4u*)(xr + (t + 5) * 32 + 4); }
    mfma13(t + 1, af);

    af = cvt8(pc0, pc1);
    if (t + 6 < 16) { pc0 = *(const f32x4u*)(xr + (t + 6) * 32); pc1 = *(const f32x4u*)(xr + (t + 6) * 32 + 4); }
    mfma13(t + 2, af);

    af = cvt8(pd0, pd1);
    if (t + 7 < 16) { pd0 = *(const f32x4u*)(xr + (t + 7) * 32); pd1 = *(const f32x4u*)(xr + (t + 7) * 32 + 4); }
    mfma13(t + 3, af);
  }

  // tail slab t=16: only k=512 is real (Wf also zero-padded past k=513)
  {
    short8 af = (short8){0, 0, 0, 0, 0, 0, 0, 0};
    if (kg == 0) af[0] = (short)f2bf(xr[512]);  // xr has +kg*8; kg==0 only
    mfma13(16, af);
  }

  unsigned short* xrow = xg + (size_t)(m0 + arow) * G_SZ;
#pragma unroll
  for (int nt = 0; nt < 13; nt++) {
    int nb = nt * 16 + kg * 4;
    if (nt < 12 || kg < 2) {  // n < 200
      float4 bi = *(const float4*)&bih[nb];
      ushort4 o;
      o.x = f2bf(acc[nt][0] + bi.x);
      o.y = f2bf(acc[nt][1] + bi.y);
      o.z = f2bf(acc[nt][2] + bi.z);
      o.w = f2bf(acc[nt][3] + bi.w);
      *(ushort4*)(xrow + nb) = o;
    }
  }
}

// ------------------------------------------------------------- K2: recurrence
__device__ __forceinline__ float sig_f(float v) {
  return 1.0f / (1.0f + __expf(-v));
}
__device__ __forceinline__ float tanh_f(float v) {
  return 2.0f / (1.0f + __expf(-2.0f * v)) - 1.0f;
}

// ONE WAVE per t; lane j owns h_j and computes ALL FOUR gate rows (4 dots of 50
// as packed f32x2 FMA).  Removes the 4-wave barrier AND the gact LDS exchange
// from the old structure.  The only per-step communication: in-wave h write ->
// uniform-address broadcast read (same-wave DS ops process in issue order;
// compiler inserts lgkmcnt -- no __syncthreads in the kernel).
// Chain-bound, so low occupancy (512 waves) is irrelevant.
// w2[4][25] f32x2 = 200 VGPRs; __launch_bounds__(64,1) allows up to 512.
__global__ __launch_bounds__(64, 1) void lstm_rec(
    const unsigned short* __restrict__ xg, const float* __restrict__ Whh,
    const float* __restrict__ bhh, unsigned short* __restrict__ hs_b) {
  int t = blockIdx.x;
  int j = threadIdx.x;                  // 0..63
  int jc = (j < H_SZ) ? j : (H_SZ - 1);
  __shared__ __align__(16) float h_sh[64];

  f32x2 w2[4][25];
  float bh[4];
#pragma unroll
  for (int g = 0; g < 4; g++) {
    const float* wr = Whh + (size_t)(g * H_SZ + jc) * H_SZ;
    bh[g] = bhh[g * H_SZ + jc];
#pragma unroll
    for (int k = 0; k < 25; k++) w2[g][k] = *(const f32x2*)(wr + 2 * k);
  }

  h_sh[j] = 0.f;
  float c = 0.f;

  const size_t bstr = (size_t)T_SZ * G_SZ;
  const unsigned short* xp = xg + (size_t)t * G_SZ + jc;

  // 8-step-deep xg prefetch: two chunks of 4 steps x 4 gates, named arrays,
  // all indices static after unroll.
  unsigned short rA[16], rB[16];
#pragma unroll
  for (int q = 0; q < 4; q++)
#pragma unroll
    for (int g = 0; g < 4; g++) rA[q * 4 + g] = xp[(size_t)q * bstr + g * H_SZ];
#pragma unroll
  for (int q = 0; q < 4; q++)
#pragma unroll
    for (int g = 0; g < 4; g++) rB[q * 4 + g] = xp[(size_t)(4 + q) * bstr + g * H_SZ];

#pragma unroll 1
  for (int b0 = 0; b0 < B_SZ; b0 += 8) {
    float xfA[16], xfB[16];
#pragma unroll
    for (int q = 0; q < 16; q++) xfA[q] = bf2f(rA[q]);
    if (b0 + 8 < B_SZ) {
#pragma unroll
      for (int q = 0; q < 4; q++)
#pragma unroll
        for (int g = 0; g < 4; g++)
          rA[q * 4 + g] = xp[(size_t)(b0 + 8 + q) * bstr + g * H_SZ];
    }
#pragma unroll
    for (int q = 0; q < 16; q++) xfB[q] = bf2f(rB[q]);
    if (b0 + 12 < B_SZ) {
#pragma unroll
      for (int q = 0; q < 4; q++)
#pragma unroll
        for (int g = 0; g < 4; g++)
          rB[q * 4 + g] = xp[(size_t)(b0 + 12 + q) * bstr + g * H_SZ];
    }

#pragma unroll
    for (int u = 0; u < 8; u++) {
      f32x2 aa[4], ab[4];
#pragma unroll
      for (int g = 0; g < 4; g++) {
        float x0 = (u < 4) ? xfA[u * 4 + g] : xfB[(u - 4) * 4 + g];
        aa[g] = (f32x2){x0 + bh[g], 0.f};
        ab[g] = (f32x2){0.f, 0.f};
      }

      // h broadcast: 12 x b128 + 1 x b64, wave-uniform addresses
      const float4* h4 = (const float4*)h_sh;
#pragma unroll
      for (int kq = 0; kq < 12; kq++) {
        float4 hv = h4[kq];
        f32x2 hlo = (f32x2){hv.x, hv.y};
        f32x2 hhi = (f32x2){hv.z, hv.w};
#pragma unroll
        for (int g = 0; g < 4; g++) {
          aa[g] = __builtin_elementwise_fma(hlo, w2[g][2 * kq], aa[g]);
          ab[g] = __builtin_elementwise_fma(hhi, w2[g][2 * kq + 1], ab[g]);
        }
      }
      {
        f32x2 hl = *(const f32x2*)(h_sh + 48);
#pragma unroll
        for (int g = 0; g < 4; g++)
          aa[g] = __builtin_elementwise_fma(hl, w2[g][24], aa[g]);
      }

      float av0 = (aa[0][0] + ab[0][0]) + (aa[0][1] + ab[0][1]);
      float av1 = (aa[1][0] + ab[1][0]) + (aa[1][1] + ab[1][1]);
      float av2 = (aa[2][0] + ab[2][0]) + (aa[2][1] + ab[2][1]);
      float av3 = (aa[3][0] + ab[3][0]) + (aa[3][1] + ab[3][1]);

      float iv = sig_f(av0);
      float fv = sig_f(av1);
      float gv = tanh_f(av2);
      float ov = sig_f(av3);
      c = fmaf(fv, c, iv * gv);
      float h = ov * tanh_f(c);
      float hval = (j < H_SZ) ? h : 0.f;

      h_sh[j] = hval;  // in-wave DS ordering; no barrier needed
      int b = b0 + u;
      hs_b[((size_t)b * T_SZ + t) * 64 + j] = f2bf(hval);  // zero-padded cols
    }
  }
}

// ------------------------------------------------------------ K3: out GEMM
// out(32768 x 513, fp32) = hs_b(32768 x 64, bf16, k-padded) @ Wout^T + b_out.
// Full unroll + __launch_bounds__(256,2): lets the scheduler hoist the
// L2-resident Wf loads deep ahead of their MFMAs.
__global__ __launch_bounds__(256, 2) void gemm_out_mfma(
    const unsigned short* __restrict__ hs_b,
    const unsigned short* __restrict__ Wf, const float* __restrict__ bout,
    float* __restrict__ out) {
  int wave = threadIdx.x >> 6;
  int lane = threadIdx.x & 63;
  int m0 = blockIdx.x * 64 + wave * 16;
  int arow = lane & 15;  // m within tile
  int kg = lane >> 4;

  const short8* Af = (const short8*)(hs_b + (size_t)(m0 + arow) * 64);
  short8 af0 = Af[kg];      // k = kg*8
  short8 af1 = Af[4 + kg];  // k = 32 + kg*8
  const short8* Bf = (const short8*)Wf;
  float* orow = out + (size_t)(m0 + arow) * F_SZ;

#pragma unroll
  for (int nt = 0; nt < 33; nt++) {
    short8 bf0 = Bf[nt * 64 + lane];
    short8 bf1 = Bf[(33 + nt) * 64 + lane];
    f32x4 acc = (f32x4){0.f, 0.f, 0.f, 0.f};
    acc = __builtin_amdgcn_mfma_f32_16x16x32_bf16(bf0, af0, acc, 0, 0, 0);
    acc = __builtin_amdgcn_mfma_f32_16x16x32_bf16(bf1, af1, acc, 0, 0, 0);
    if (nt < 32) {
      int f0 = nt * 16 + kg * 4;
      float4 bv = *(const float4*)&bout[f0];
      float4 o = make_float4(acc[0] + bv.x, acc[1] + bv.y, acc[2] + bv.z,
                             acc[3] + bv.w);
      *(float4*)(orow + f0) = o;  // rows 4B-aligned; HW handles unaligned x4
    } else if (kg == 0) {
      orow[512] = acc[0] + bout[512];  // nt=32: only f=512 real
    }
  }
}

extern "C" void kernel_launch(void* const* d_in, const int* in_sizes, int n_in,
                              void* d_out, int out_size, void* d_ws,
                              size_t ws_size, hipStream_t stream) {
  const float* x = (const float*)d_in[0];
  const float* Wih = (const float*)d_in[1];
  const float* Whh = (const float*)d_in[2];
  const float* bih = (const float*)d_in[3];
  const float* bhh = (const float*)d_in[4];
  const float* Wout = (const float*)d_in[5];
  const float* bout = (const float*)d_in[6];
  float* out = (float*)d_out;

  // ws layout (17.6 MB):
  //   xg_b   : bf16 [32768][200]   13,107,200 B @ 0
  //   hs_b   : bf16 [32768][64]     4,194,304 B @ 13,107,200
  //   Wf_ih  : 17*13*64 frags         226,304 B @ 17,301,504
  //   Wf_out : 2*33*64 frags           67,584 B @ 17,527,808
  unsigned short* xg_b = (unsigned short*)d_ws;
  unsigned short* hs_b = (unsigned short*)((char*)d_ws + 13107200);
  unsigned short* Wf_ih = (unsigned short*)((char*)d_ws + 17301504);
  unsigned short* Wf_out = (unsigned short*)((char*)d_ws + 17527808);

  conv_weights<<<(NF_IH + NF_OUT + 255) / 256, 256, 0, stream>>>(Wih, Wout,
                                                                 Wf_ih, Wf_out);

  gemm_xg_mfma<<<M_SZ / 64, 256, 0, stream>>>(x, Wf_ih, bih, xg_b);

  lstm_rec<<<T_SZ, 64, 0, stream>>>(xg_b, Whh, bhh, hs_b);

  gemm_out_mfma<<<M_SZ / 64, 256, 0, stream>>>(hs_b, Wf_out, bout, out);
}